// Round 6
// baseline (36.253 us; speedup 1.0000x reference)
//
#include <hip/hip_runtime.h>
#include <math.h>

#define B_    512
#define C_    10
#define HW_   4096
#define NT    512       // 8 waves/block, 1 block per sample, 8 px/thread
#define NBMP  313       // ceil(10^4 / 32) presence-bitmap words

// Zero-initialized at module load; winner block restores it to 0 every call.
__device__ unsigned int g_ticket = 0;

__device__ __forceinline__ float wave_sum_f(float v) {
#pragma unroll
    for (int off = 32; off > 0; off >>= 1) v += __shfl_xor(v, off, 64);
    return v;
}
// Block-wide sum over NT threads; valid on tid==0 only.
__device__ __forceinline__ float block_sum(float v, volatile float* sp, int tid) {
    v = wave_sum_f(v);
    __syncthreads();
    if ((tid & 63) == 0) sp[tid >> 6] = v;
    __syncthreads();
    float s = 0.f;
    if (tid == 0) {
#pragma unroll
        for (int i = 0; i < NT / 64; ++i) s += sp[i];
    }
    return s;
}
// Agent-scope publish/consume: reach the cross-XCD coherence point without
// __threadfence's L2 writeback.
__device__ __forceinline__ void agst(float* p, float v) {
    __hip_atomic_store(p, v, __ATOMIC_RELAXED, __HIP_MEMORY_SCOPE_AGENT);
}
__device__ __forceinline__ float agld(const float* p) {
    return __hip_atomic_load(p, __ATOMIC_RELAXED, __HIP_MEMORY_SCOPE_AGENT);
}

// Process 4 pixels from float4 channel array X, targets T4, inputs I4.
// Accumulates focal/eqc/dfc/cmask; writes packed pred_idx to s_pred32[SLOT].
#define PROC4(X, T4, I4, SLOT)                                              \
    {                                                                       \
        unsigned pack = 0u;                                                 \
        _Pragma("unroll")                                                   \
        for (int e = 0; e < 4; ++e) {                                       \
            const int t  = (e==0)?T4.x:(e==1)?T4.y:(e==2)?T4.z:T4.w;        \
            const int iv = (e==0)?I4.x:(e==1)?I4.y:(e==2)?I4.z:I4.w;        \
            cmask |= 1u << t;                                               \
            float x0 = (e==0)?X[0].x:(e==1)?X[0].y:(e==2)?X[0].z:X[0].w;    \
            float mx = x0; int am = 0;                                      \
            float xs[C_];                                                   \
            xs[0] = x0;                                                     \
            _Pragma("unroll")                                               \
            for (int c = 1; c < C_; ++c) {                                  \
                const float xc = (e==0)?X[c].x:(e==1)?X[c].y:(e==2)?X[c].z:X[c].w; \
                xs[c] = xc;                                                 \
                if (xc > mx) { mx = xc; am = c; }  /* strict >: first max */\
            }                                                               \
            float se = 0.f, xt = 0.f;                                       \
            _Pragma("unroll")                                               \
            for (int c = 0; c < C_; ++c) {                                  \
                se += __expf(xs[c] - mx);                                   \
                if (c == t) xt = xs[c];                                     \
            }                                                               \
            const float ce = (mx + __logf(se)) - xt;                        \
            const float pt = __expf(-ce);                                   \
            const float om = 1.f - pt;                                      \
            focal += om * om * ce;                                          \
            eqc += (am == t);                                               \
            dfc += (am != iv);                                              \
            pack |= (unsigned)am << (8 * e);                                \
        }                                                                   \
        s_pred32[SLOT] = pack;                                              \
    }

__global__ __launch_bounds__(NT, 4) void loss_all(
    const float* __restrict__ pred, const int* __restrict__ tgt,
    const int* __restrict__ inp, const float* __restrict__ strat,
    float* __restrict__ ws, float* __restrict__ out)
{
    const int b   = blockIdx.x;
    const int tid = threadIdx.x;

    __shared__ unsigned int s_pred32[HW_ / 4];   // packed pred_idx bytes
    __shared__ unsigned int s_bmp[NBMP];
    __shared__ float        s_red[8][5];
    __shared__ unsigned int s_cmask;
    __shared__ int          s_last;

    if (tid < NBMP) s_bmp[tid] = 0u;
    if (tid == 0) s_cmask = 0u;

    const float* pb = pred + (size_t)b * (C_ * HW_);
    const int p0 = tid * 4;            // first 4 px
    const int p1 = (NT + tid) * 4;     // second 4 px

    // ---- hoist ALL global loads: 20x dwordx4 + 4x int4 + strat ----
    float4 xa[C_], xb[C_];
#pragma unroll
    for (int c = 0; c < C_; ++c) xa[c] = *(const float4*)(pb + c * HW_ + p0);
#pragma unroll
    for (int c = 0; c < C_; ++c) xb[c] = *(const float4*)(pb + c * HW_ + p1);
    const int4 ta = *(const int4*)(tgt + b * HW_ + p0);
    const int4 tb4 = *(const int4*)(tgt + b * HW_ + p1);
    const int4 ia = *(const int4*)(inp + b * HW_ + p0);
    const int4 ib4 = *(const int4*)(inp + b * HW_ + p1);
    const float sv = (tid < 128) ? strat[b * 128 + tid] : 0.f;

    float focal = 0.f;
    unsigned cmask = 0u;
    int eqc = 0, dfc = 0;

    PROC4(xa, ta, ia, tid)
    PROC4(xb, tb4, ib4, NT + tid)

    const float cre = (tid < 128) ? 1.f / (1.f + __expf(-sv)) : 0.f;

    __syncthreads();   // s_pred32 complete, s_bmp zeroed

    // 2x2-window diversity over packed dwords: 63 rows x 16 dwords = 1008 slots
    for (int idx = tid; idx < 1008; idx += NT) {
        const int c4 = (idx & 15) << 2;            // 0,4,...,60
        const unsigned w0 = s_pred32[idx];
        const unsigned w1 = s_pred32[idx + 16];
        const unsigned n0 = (c4 < 60) ? s_pred32[idx + 1]  : 0u;
        const unsigned n1 = (c4 < 60) ? s_pred32[idx + 17] : 0u;
        const unsigned a0 =  w0        & 0xffu, a1 = (w0 >>  8) & 0xffu,
                       a2 = (w0 >> 16) & 0xffu, a3 = (w0 >> 24) & 0xffu,
                       a4 =  n0        & 0xffu;
        const unsigned b0 =  w1        & 0xffu, b1 = (w1 >>  8) & 0xffu,
                       b2 = (w1 >> 16) & 0xffu, b3 = (w1 >> 24) & 0xffu,
                       b4 =  n1        & 0xffu;
        unsigned code;
        code = a0 * 1000u + a1 * 100u + b0 * 10u + b1;
        atomicOr(&s_bmp[code >> 5], 1u << (code & 31u));
        code = a1 * 1000u + a2 * 100u + b1 * 10u + b2;
        atomicOr(&s_bmp[code >> 5], 1u << (code & 31u));
        code = a2 * 1000u + a3 * 100u + b2 * 10u + b3;
        atomicOr(&s_bmp[code >> 5], 1u << (code & 31u));
        if (c4 < 60) {
            code = a3 * 1000u + a4 * 100u + b3 * 10u + b4;
            atomicOr(&s_bmp[code >> 5], 1u << (code & 31u));
        }
    }
    __syncthreads();

    const int nu = (tid < NBMP) ? __popc(s_bmp[tid]) : 0;

    // per-sample reductions (8 waves): 5 shfl-reduces + colmask OR
    const float rf = wave_sum_f(focal);
    const float re = wave_sum_f((float)eqc);
    const float rd = wave_sum_f((float)dfc);
    const float rc = wave_sum_f(cre);
    const float rn = wave_sum_f((float)nu);
#pragma unroll
    for (int off = 32; off > 0; off >>= 1)
        cmask |= (unsigned)__shfl_xor((int)cmask, off, 64);

    const int wv = tid >> 6;
    if ((tid & 63) == 0) {
        s_red[wv][0] = rf; s_red[wv][1] = re; s_red[wv][2] = rd;
        s_red[wv][3] = rc; s_red[wv][4] = rn;
        atomicOr(&s_cmask, cmask);
    }
    __syncthreads();
    if (tid == 0) {
        float F = 0.f, E = 0.f, D = 0.f, CR = 0.f, NU = 0.f;
#pragma unroll
        for (int i = 0; i < 8; ++i) {
            F += s_red[i][0]; E += s_red[i][1]; D += s_red[i][2];
            CR += s_red[i][3]; NU += s_red[i][4];
        }
        const int uc = __popc(s_cmask);
        const float sw = (uc > 3) ? 1.2f : 1.0f;   // strategic weight
        agst(ws + 0 * B_ + b, F * sw);
        agst(ws + 1 * B_ + b, E);                             // intersection
        agst(ws + 2 * B_ + b, (E == 4096.f) ? 1.f : 0.f);     // exact strict
        agst(ws + 3 * B_ + b, (D == 0.f) ? 1.f : 0.f);        // copy flag
        agst(ws + 4 * B_ + b, NU);                            // unique codes
        agst(ws + 5 * B_ + b, CR);                            // sigmoid sum
        // acq_rel RMW: releases our stores, acquires everyone else's.
        const unsigned old = __hip_atomic_fetch_add(
            &g_ticket, 1u, __ATOMIC_ACQ_REL, __HIP_MEMORY_SCOPE_AGENT);
        const int last = (old == (unsigned)(B_ - 1));
        if (last)  // self-reset so every call (incl. graph replays) starts at 0
            __hip_atomic_fetch_add(&g_ticket, (unsigned)-B_,
                                   __ATOMIC_RELAXED, __HIP_MEMORY_SCOPE_AGENT);
        s_last = last;
    }
    __syncthreads();
    if (!s_last) return;

    // ---- last block: epilogue over the 512 per-sample partials ----
    const float focal_b = agld(ws + 0 * B_ + tid);
    const float inter   = agld(ws + 1 * B_ + tid);
    const float strict  = agld(ws + 2 * B_ + tid);
    const float copyf   = agld(ws + 3 * B_ + tid);
    const float nuv     = agld(ws + 4 * B_ + tid);
    const float crev    = agld(ws + 5 * B_ + tid);

    const float iou  = inter * (1.f / 4096.f);
    const float comb = 0.2f * strict + 0.8f * iou;
    const float divb = nuv * (1.f / 3969.f);

    volatile float* sp = &s_red[0][0];
    const float focal_s = block_sum(focal_b, sp, tid);
    const float comb_s  = block_sum(comb, sp, tid);
    const float iou_s   = block_sum(iou, sp, tid);
    const float copy_s  = block_sum(copyf, sp, tid);
    const float div_s   = block_sum(divb, sp, tid);
    const float cre_s   = block_sum(crev, sp, tid);

    if (tid == 0) {
        const float focal_loss        = focal_s / (512.f * 4096.f);
        const float comb_mean         = comb_s / 512.f;
        const float exact_count       = comb_s;
        const float exact_bonus       = fmaxf(-comb_mean * 5.f, -3.f);
        const float transform_penalty = (copy_s / 512.f) * 0.2f;
        const float creativity        = (cre_s / (512.f * 128.f)) * 0.15f;
        const float diversity         = (div_s / 512.f) * 0.02f;
        const float gcb               = comb_mean * 0.05f;  // grid factor == 1

        float total = focal_loss + transform_penalty + exact_bonus
                    - creativity - diversity - gcb;
        if (isnan(total) || isinf(total)) total = fminf(focal_loss, 10.f);

        out[0] = total;
        out[1] = focal_loss;
        out[2] = transform_penalty;
        out[3] = exact_bonus;
        out[4] = exact_count;
        out[5] = exact_count;   // combined_matches.sum() appears twice
        out[6] = iou_s / 512.f;
        out[7] = creativity;
        out[8] = diversity;
        out[9] = gcb;
    }
}

extern "C" void kernel_launch(void* const* d_in, const int* in_sizes, int n_in,
                              void* d_out, int out_size, void* d_ws, size_t ws_size,
                              hipStream_t stream)
{
    const float* pred  = (const float*)d_in[0];
    const int*   tgt   = (const int*)d_in[1];
    const int*   inp   = (const int*)d_in[2];
    const float* strat = (const float*)d_in[3];
    float* ws  = (float*)d_ws;
    float* out = (float*)d_out;

    hipLaunchKernelGGL(loss_all, dim3(B_), dim3(NT), 0, stream,
                       pred, tgt, inp, strat, ws, out);
}

// Round 7
// 26.958 us; speedup vs baseline: 1.3448x; 1.3448x over previous
//
#include <hip/hip_runtime.h>
#include <math.h>

#define B_    512
#define C_    10
#define HW_   4096
#define NT    512       // 8 waves/block, 1 block per sample, 8 px/thread
#define NBMP  313       // ceil(10^4 / 32) presence-bitmap words

__device__ __forceinline__ float wave_sum_f(float v) {
#pragma unroll
    for (int off = 32; off > 0; off >>= 1) v += __shfl_xor(v, off, 64);
    return v;
}

// Process 4 pixels from float4 channel array X, targets T4, inputs I4.
// Accumulates focal/eqc/dfc/cmask; writes packed pred_idx to s_pred32[SLOT].
#define PROC4(X, T4, I4, SLOT)                                              \
    {                                                                       \
        unsigned pack = 0u;                                                 \
        _Pragma("unroll")                                                   \
        for (int e = 0; e < 4; ++e) {                                       \
            const int t  = (e==0)?T4.x:(e==1)?T4.y:(e==2)?T4.z:T4.w;        \
            const int iv = (e==0)?I4.x:(e==1)?I4.y:(e==2)?I4.z:I4.w;        \
            cmask |= 1u << t;                                               \
            float x0 = (e==0)?X[0].x:(e==1)?X[0].y:(e==2)?X[0].z:X[0].w;    \
            float mx = x0; int am = 0;                                      \
            float xs[C_];                                                   \
            xs[0] = x0;                                                     \
            _Pragma("unroll")                                               \
            for (int c = 1; c < C_; ++c) {                                  \
                const float xc = (e==0)?X[c].x:(e==1)?X[c].y:(e==2)?X[c].z:X[c].w; \
                xs[c] = xc;                                                 \
                if (xc > mx) { mx = xc; am = c; }  /* strict >: first max */\
            }                                                               \
            float se = 0.f, xt = 0.f;                                       \
            _Pragma("unroll")                                               \
            for (int c = 0; c < C_; ++c) {                                  \
                se += __expf(xs[c] - mx);                                   \
                if (c == t) xt = xs[c];                                     \
            }                                                               \
            const float ce = (mx + __logf(se)) - xt;                        \
            const float pt = __expf(-ce);                                   \
            const float om = 1.f - pt;                                      \
            focal += om * om * ce;                                          \
            eqc += (am == t);                                               \
            dfc += (am != iv);                                              \
            pack |= (unsigned)am << (8 * e);                                \
        }                                                                   \
        s_pred32[SLOT] = pack;                                              \
    }

__global__ __launch_bounds__(NT, 4) void loss_main(
    const float* __restrict__ pred, const int* __restrict__ tgt,
    const int* __restrict__ inp, const float* __restrict__ strat,
    float* __restrict__ ws)
{
    const int b   = blockIdx.x;
    const int tid = threadIdx.x;

    __shared__ unsigned int s_pred32[HW_ / 4];   // packed pred_idx bytes
    __shared__ unsigned int s_bmp[NBMP];
    __shared__ float        s_red[8][5];
    __shared__ unsigned int s_cmask;

    if (tid < NBMP) s_bmp[tid] = 0u;
    if (tid == 0) s_cmask = 0u;

    const float* pb = pred + (size_t)b * (C_ * HW_);
    const int p0 = tid * 4;            // first 4 px
    const int p1 = (NT + tid) * 4;     // second 4 px

    // ---- hoisted loads, ordered so chunk-A compute can start while the
    // chunk-B stream is still in flight (A deps issue first) ----
    const int4 ta = *(const int4*)(tgt + b * HW_ + p0);
    const int4 ia = *(const int4*)(inp + b * HW_ + p0);
    float4 xa[C_], xb[C_];
#pragma unroll
    for (int c = 0; c < C_; ++c) xa[c] = *(const float4*)(pb + c * HW_ + p0);
    const int4 tb4 = *(const int4*)(tgt + b * HW_ + p1);
    const int4 ib4 = *(const int4*)(inp + b * HW_ + p1);
#pragma unroll
    for (int c = 0; c < C_; ++c) xb[c] = *(const float4*)(pb + c * HW_ + p1);
    const float sv = (tid < 128) ? strat[b * 128 + tid] : 0.f;

    float focal = 0.f;
    unsigned cmask = 0u;
    int eqc = 0, dfc = 0;

    PROC4(xa, ta, ia, tid)
    PROC4(xb, tb4, ib4, NT + tid)

    const float cre = (tid < 128) ? 1.f / (1.f + __expf(-sv)) : 0.f;

    __syncthreads();   // s_pred32 complete, s_bmp zeroed

    // 2x2-window diversity over packed dwords: 63 rows x 16 dwords = 1008 slots
    for (int idx = tid; idx < 1008; idx += NT) {
        const int c4 = (idx & 15) << 2;            // 0,4,...,60
        const unsigned w0 = s_pred32[idx];
        const unsigned w1 = s_pred32[idx + 16];
        const unsigned n0 = (c4 < 60) ? s_pred32[idx + 1]  : 0u;
        const unsigned n1 = (c4 < 60) ? s_pred32[idx + 17] : 0u;
        const unsigned a0 =  w0        & 0xffu, a1 = (w0 >>  8) & 0xffu,
                       a2 = (w0 >> 16) & 0xffu, a3 = (w0 >> 24) & 0xffu,
                       a4 =  n0        & 0xffu;
        const unsigned b0 =  w1        & 0xffu, b1 = (w1 >>  8) & 0xffu,
                       b2 = (w1 >> 16) & 0xffu, b3 = (w1 >> 24) & 0xffu,
                       b4 =  n1        & 0xffu;
        unsigned code;
        code = a0 * 1000u + a1 * 100u + b0 * 10u + b1;
        atomicOr(&s_bmp[code >> 5], 1u << (code & 31u));
        code = a1 * 1000u + a2 * 100u + b1 * 10u + b2;
        atomicOr(&s_bmp[code >> 5], 1u << (code & 31u));
        code = a2 * 1000u + a3 * 100u + b2 * 10u + b3;
        atomicOr(&s_bmp[code >> 5], 1u << (code & 31u));
        if (c4 < 60) {
            code = a3 * 1000u + a4 * 100u + b3 * 10u + b4;
            atomicOr(&s_bmp[code >> 5], 1u << (code & 31u));
        }
    }
    __syncthreads();

    const int nu = (tid < NBMP) ? __popc(s_bmp[tid]) : 0;

    // per-sample reductions (8 waves): 5 shfl-reduces + colmask OR
    const float rf = wave_sum_f(focal);
    const float re = wave_sum_f((float)eqc);
    const float rd = wave_sum_f((float)dfc);
    const float rc = wave_sum_f(cre);
    const float rn = wave_sum_f((float)nu);
#pragma unroll
    for (int off = 32; off > 0; off >>= 1)
        cmask |= (unsigned)__shfl_xor((int)cmask, off, 64);

    const int wv = tid >> 6;
    if ((tid & 63) == 0) {
        s_red[wv][0] = rf; s_red[wv][1] = re; s_red[wv][2] = rd;
        s_red[wv][3] = rc; s_red[wv][4] = rn;
        atomicOr(&s_cmask, cmask);
    }
    __syncthreads();
    if (tid == 0) {
        float F = 0.f, E = 0.f, D = 0.f, CR = 0.f, NU = 0.f;
#pragma unroll
        for (int i = 0; i < 8; ++i) {
            F += s_red[i][0]; E += s_red[i][1]; D += s_red[i][2];
            CR += s_red[i][3]; NU += s_red[i][4];
        }
        const int uc = __popc(s_cmask);
        const float sw = (uc > 3) ? 1.2f : 1.0f;   // strategic weight
        ws[0 * B_ + b] = F * sw;
        ws[1 * B_ + b] = E;                               // intersection
        ws[2 * B_ + b] = (E == 4096.f) ? 1.f : 0.f;       // exact strict
        ws[3 * B_ + b] = (D == 0.f) ? 1.f : 0.f;          // copy flag
        ws[4 * B_ + b] = NU;                              // unique 2x2 codes
        ws[5 * B_ + b] = CR;                              // sigmoid sum
    }
}

__global__ __launch_bounds__(NT) void loss_final(
    const float* __restrict__ ws, float* __restrict__ out)
{
    const int tid = threadIdx.x;  // == b
    __shared__ float s_red[8][6];

    const float focal_b = ws[0 * B_ + tid];
    const float inter   = ws[1 * B_ + tid];
    const float strict  = ws[2 * B_ + tid];
    const float copyf   = ws[3 * B_ + tid];
    const float nu      = ws[4 * B_ + tid];
    const float cre     = ws[5 * B_ + tid];

    const float iou  = inter * (1.f / 4096.f);
    const float comb = 0.2f * strict + 0.8f * iou;
    const float divb = nu * (1.f / 3969.f);

    // fused 6-value reduction: one wave pass + ONE barrier
    const float r0 = wave_sum_f(focal_b);
    const float r1 = wave_sum_f(comb);
    const float r2 = wave_sum_f(iou);
    const float r3 = wave_sum_f(copyf);
    const float r4 = wave_sum_f(divb);
    const float r5 = wave_sum_f(cre);
    const int wv = tid >> 6;
    if ((tid & 63) == 0) {
        s_red[wv][0] = r0; s_red[wv][1] = r1; s_red[wv][2] = r2;
        s_red[wv][3] = r3; s_red[wv][4] = r4; s_red[wv][5] = r5;
    }
    __syncthreads();

    if (tid == 0) {
        float focal_s = 0.f, comb_s = 0.f, iou_s = 0.f,
              copy_s = 0.f, div_s = 0.f, cre_s = 0.f;
#pragma unroll
        for (int i = 0; i < 8; ++i) {
            focal_s += s_red[i][0]; comb_s += s_red[i][1]; iou_s += s_red[i][2];
            copy_s  += s_red[i][3]; div_s  += s_red[i][4]; cre_s += s_red[i][5];
        }
        const float focal_loss        = focal_s / (512.f * 4096.f);
        const float comb_mean         = comb_s / 512.f;
        const float exact_count       = comb_s;
        const float exact_bonus       = fmaxf(-comb_mean * 5.f, -3.f);
        const float transform_penalty = (copy_s / 512.f) * 0.2f;
        const float creativity        = (cre_s / (512.f * 128.f)) * 0.15f;
        const float diversity         = (div_s / 512.f) * 0.02f;
        const float gcb               = comb_mean * 0.05f;  // grid factor == 1

        float total = focal_loss + transform_penalty + exact_bonus
                    - creativity - diversity - gcb;
        if (isnan(total) || isinf(total)) total = fminf(focal_loss, 10.f);

        out[0] = total;
        out[1] = focal_loss;
        out[2] = transform_penalty;
        out[3] = exact_bonus;
        out[4] = exact_count;
        out[5] = exact_count;   // combined_matches.sum() appears twice
        out[6] = iou_s / 512.f;
        out[7] = creativity;
        out[8] = diversity;
        out[9] = gcb;
    }
}

extern "C" void kernel_launch(void* const* d_in, const int* in_sizes, int n_in,
                              void* d_out, int out_size, void* d_ws, size_t ws_size,
                              hipStream_t stream)
{
    const float* pred  = (const float*)d_in[0];
    const int*   tgt   = (const int*)d_in[1];
    const int*   inp   = (const int*)d_in[2];
    const float* strat = (const float*)d_in[3];
    float* ws  = (float*)d_ws;
    float* out = (float*)d_out;

    hipLaunchKernelGGL(loss_main, dim3(B_), dim3(NT), 0, stream,
                       pred, tgt, inp, strat, ws);
    hipLaunchKernelGGL(loss_final, dim3(1), dim3(NT), 0, stream, ws, out);
}